// Round 13
// baseline (179.995 us; speedup 1.0000x reference)
//
#include <hip/hip_runtime.h>
#include <math.h>

#define AT 24
#define ATP 32
#define HD 128
#define GD 50
#define NT 3
#define CUTOFF 10.0f
#define NK 1024        // table knots

#define KP_W 136       // padded K stride (bf16) for K=128
#define XFP 132        // xf fp32 row stride

#define SZ_BIG (128*KP_W)
#define WS_LIN1(t) ((t)*SZ_BIG)
#define WS_LIN2(t) ((3+(t))*SZ_BIG)
#define WS_LIN(t)  ((6+(t))*SZ_BIG)
#define WS_OW1     (9*SZ_BIG)
#define WS_TAB     (9*SZ_BIG + 64*KP_W)   // tab: [NT][NK][256] u16: per col-pair [T0,D0,T1,D1]

typedef __attribute__((ext_vector_type(8))) short short8;
typedef __attribute__((ext_vector_type(4))) float f32x4;
typedef __attribute__((ext_vector_type(2))) float f32x2;

__device__ __forceinline__ unsigned short f2bf(float x) {
    unsigned int u = __float_as_uint(x);
    return (unsigned short)((u + 0x7fffu + ((u >> 16) & 1u)) >> 16);
}
__device__ __forceinline__ float sspf(float x) {
    return fmaxf(x, 0.0f) + __logf(1.0f + __expf(-fabsf(x))) - 0.69314718055994531f;
}

// interp: td = (T lo16, D hi16) bf16 pair; fp = (1.0 lo16, f hi16) bf16 pair.
// result = T + f*D
#if __has_builtin(__builtin_amdgcn_fdot2_f32_bf16)
typedef __attribute__((ext_vector_type(2))) __bf16 bfv2;
__device__ __forceinline__ float dot2bf(unsigned td, unsigned fp) {
    return __builtin_amdgcn_fdot2_f32_bf16(
        __builtin_bit_cast(bfv2, td), __builtin_bit_cast(bfv2, fp), 0.0f, false);
}
#else
__device__ __forceinline__ float dot2bf(unsigned td, unsigned fp) {
    float t = __uint_as_float(td << 16);
    float d = __uint_as_float(td & 0xFFFF0000u);
    float f = __uint_as_float(fp & 0xFFFF0000u);
    return fmaf(f, d, t);
}
#endif

// async global->LDS; bytes multiple of 1024; 512 threads
__device__ __forceinline__ void g2l_async(const void* g, void* l, int bytes, int tid) {
    int w = tid >> 6, lane = tid & 63;
    const char* gc = (const char*)g + lane * 16;
    char* lc = (char*)l + lane * 16;
    for (int ofs = w * 1024; ofs < bytes; ofs += 8192) {
        __builtin_amdgcn_global_load_lds(
            (const __attribute__((address_space(1))) unsigned int*)(gc + ofs),
            (__attribute__((address_space(3))) unsigned int*)(lc + ofs), 16, 0, 0);
    }
}

__device__ __forceinline__ f32x4 mfma16(short8 a, short8 b, f32x4 c) {
    return __builtin_amdgcn_mfma_f32_16x16x32_bf16(a, b, c, 0, 0, 0);
}

// 16x(2x16) GEMM from LDS: A rows rt*16, B cols cn*16 + c*64
template<int NKT>
__device__ __forceinline__ void gemm2(const unsigned short* A, const unsigned short* B,
                                      int q, f32x4* acc)
{
#pragma unroll
    for (int kt = 0; kt < NKT; ++kt) {
        short8 a  = *(const short8*)(A + kt * 32 + q * 8);
        short8 b0 = *(const short8*)(B + kt * 32 + q * 8);
        short8 b1 = *(const short8*)(B + 64 * KP_W + kt * 32 + q * 8);
        acc[0] = mfma16(a, b0, acc[0]);
        acc[1] = mfma16(a, b1, acc[1]);
    }
}

// ---- edge pipeline: 6 items (2 s-parity steps x 3 dst) per stage ----
__device__ __forceinline__ void eissue(const char* tbase, const unsigned* eoff_s,
                                       int w, int hl, int vlo, int s0, uint4 (&buf)[6]) {
#pragma unroll
    for (int pp = 0; pp < 2; ++pp)
#pragma unroll
        for (int r = 0; r < 3; ++r) {
            int s = s0 + 2 * pp + hl;
            unsigned off = eoff_s[(w + 8 * r) * AT + s];
            buf[pp * 3 + r] = *(const uint4*)(tbase + (off + vlo));
        }
}

__device__ __forceinline__ void ecomp(const float* xf_s, const unsigned* efpk_s,
                                      int w, int hl, int l32, int s0,
                                      const uint4 (&buf)[6], f32x4 (&ag)[3]) {
#pragma unroll
    for (int pp = 0; pp < 2; ++pp) {
        int s = s0 + 2 * pp + hl;
        f32x4 xv = *(const f32x4*)&xf_s[s * XFP + l32 * 4];
#pragma unroll
        for (int r = 0; r < 3; ++r) {
            unsigned f = efpk_s[(w + 8 * r) * AT + s];
            uint4 p = buf[pp * 3 + r];
            ag[r][0] = fmaf(dot2bf(p.x, f), xv[0], ag[r][0]);
            ag[r][1] = fmaf(dot2bf(p.y, f), xv[1], ag[r][1]);
            ag[r][2] = fmaf(dot2bf(p.z, f), xv[2], ag[r][2]);
            ag[r][3] = fmaf(dot2bf(p.w, f), xv[3], ag[r][3]);
        }
    }
}

// ---- merged prep: weight transpose (blocks 0..39) + interleaved (T,D) table ----
__global__ void __launch_bounds__(256) prep(
    const float* __restrict__ lin1_w, const float* __restrict__ lin2_w,
    const float* __restrict__ lin_w,  const float* __restrict__ out_w1,
    const float* __restrict__ mlp_w1, const float* __restrict__ mlp_b1,
    const float* __restrict__ mlp_w2, const float* __restrict__ mlp_b2,
    unsigned short* __restrict__ ws)
{
    int b = blockIdx.x, tid = threadIdx.x;
    if (b < 40) {
        const float* src; unsigned short* dst; int N, n0, rows;
        if (b < 36) {
            int mat = b >> 2, slice = b & 3;
            int grp = mat / 3, t = mat - grp * 3;
            const float* bases[3] = {lin1_w, lin2_w, lin_w};
            src = bases[grp] + t * HD * HD;
            dst = ws + (grp * 3 + t) * SZ_BIG;
            N = 128; n0 = slice * 32; rows = 32;
        } else {
            src = out_w1; dst = ws + WS_OW1; N = 64; n0 = (b - 36) * 16; rows = 16;
        }
        int nn = tid & 31, kk = tid >> 5;   // kk in [0,8) -> stride 8
        if (nn < rows) {
            for (int k = kk; k < KP_W; k += 8) {
                float v = (k < HD) ? src[k * N + n0 + nn] : 0.f;
                dst[(n0 + nn) * KP_W + k] = f2bf(v);
            }
        }
        return;
    }
    // ---- table blocks: block -> (t, 8-knot slab); 9 rows (1 overlap) for deltas.
    __shared__ __align__(16) float w2s[HD * HD];      // 64 KiB, staged via global_load_lds
    __shared__ __align__(16) float ea[9][52];
    __shared__ float pacc[4][5][128];                 // per-wave partial sums
    __shared__ __align__(16) unsigned short tabst[8 * 256];

    int b2 = b - 40;                 // [0, 384)
    int t = b2 >> 7, k0 = (b2 & 127) << 3;

    // stage w2[t] (65536 B) -> LDS: 256 thr x 16B = 4KB/iter, 16 iters
    {
        const char* gc = (const char*)(mlp_w2 + t * HD * HD) + tid * 16;
        char* lc = (char*)w2s + tid * 16;
#pragma unroll
        for (int ofs = 0; ofs < 65536; ofs += 4096)
            __builtin_amdgcn_global_load_lds(
                (const __attribute__((address_space(1))) unsigned int*)(gc + ofs),
                (__attribute__((address_space(3))) unsigned int*)(lc + ofs), 16, 0, 0);
    }

    const float h = CUTOFF / (NK - 1);
    const float STEP = CUTOFF / (GD - 1);
    const float COEFF = -0.5f / (STEP * STEP);
    for (int i = tid; i < 9 * GD; i += 256) {
        int rr = i / GD, g = i - rr * GD;
        int k = min(k0 + rr, NK - 1);
        float r = (float)k * h;
        float d = r - (float)g * STEP;
        ea[rr][g] = __expf(COEFF * d * d);
    }
    __syncthreads();   // ea visible; barrier drains vmcnt(0) -> w2s ready

    int j = tid & 127, kh = tid >> 7;            // kh half: rows kh*4 .. kh*4+4
    // ---- hid in registers: rows kh*4..kh*4+4 of column j
    float pre[5];
    float bb1 = mlp_b1[t * HD + j];
#pragma unroll
    for (int rr = 0; rr < 5; ++rr) pre[rr] = bb1;
    const float* w1p = mlp_w1 + t * GD * HD + j;
    for (int g0 = 0; g0 < 48; g0 += 4) {
        f32x4 e[5];
#pragma unroll
        for (int rr = 0; rr < 5; ++rr) e[rr] = *(const f32x4*)&ea[kh * 4 + rr][g0];
        float wv[4];
#pragma unroll
        for (int gg = 0; gg < 4; ++gg) wv[gg] = w1p[(g0 + gg) * HD];
#pragma unroll
        for (int gg = 0; gg < 4; ++gg)
#pragma unroll
            for (int rr = 0; rr < 5; ++rr)
                pre[rr] = fmaf(e[rr][gg], wv[gg], pre[rr]);
    }
#pragma unroll
    for (int g = 48; g < GD; ++g) {
        float wv = w1p[g * HD];
#pragma unroll
        for (int rr = 0; rr < 5; ++rr)
            pre[rr] = fmaf(ea[kh * 4 + rr][g], wv, pre[rr]);
    }
#pragma unroll
    for (int rr = 0; rr < 5; ++rr) pre[rr] = sspf(pre[rr]);

    // ---- u-contraction: wave wv_ owns rows (wv_>>1)*4..+4, u-range (wv_&1)*64..+64.
    {
        int wv_ = tid >> 6, l = tid & 63;
        int ubase = (wv_ & 1) << 6;
        float a0[5], a1[5];
#pragma unroll
        for (int rr = 0; rr < 5; ++rr) { a0[rr] = 0.f; a1[rr] = 0.f; }
#pragma unroll 8
        for (int step = 0; step < 64; ++step) {
            int uu = ubase + step;
            float wa = w2s[uu * HD + l];
            float wb = w2s[uu * HD + l + 64];
#pragma unroll
            for (int rr = 0; rr < 5; ++rr) {
                float hv = __uint_as_float(
                    __builtin_amdgcn_readlane(__float_as_uint(pre[rr]), step));
                a0[rr] = fmaf(hv, wa, a0[rr]);
                a1[rr] = fmaf(hv, wb, a1[rr]);
            }
        }
#pragma unroll
        for (int rr = 0; rr < 5; ++rr) {
            pacc[wv_][rr][l] = a0[rr];
            pacc[wv_][rr][l + 64] = a1[rr];
        }
    }
    __syncthreads();
    // ---- finalize in original writer layout: thread (kh, j), rows kh*4+rr
    float bb2 = mlp_b2[t * HD + j];
    float Tv[5];
#pragma unroll
    for (int rr = 0; rr < 5; ++rr) {
        float s = pacc[2 * kh][rr][j] + pacc[2 * kh + 1][rr][j] + bb2;
        int k = min(k0 + kh * 4 + rr, NK - 1);
        float r = (float)k * h;
        Tv[rr] = s * 0.5f * (__cosf(r * 0.31415926535897931f) + 1.0f);
    }
#pragma unroll
    for (int rr = 0; rr < 4; ++rr) {
        int kr = kh * 4 + rr;
        int ofs = kr * 256 + (j >> 1) * 4 + (j & 1) * 2;   // [T,D] interleaved per column
        tabst[ofs]     = f2bf(Tv[rr]);
        tabst[ofs + 1] = f2bf(Tv[rr + 1] - Tv[rr]);
    }
    __syncthreads();
    // coalesced write-out: 256 thr x 16B = 4KB slab
    unsigned short* tb = ws + WS_TAB + (size_t)t * NK * 256 + k0 * 256;
    *(short8*)(tb + tid * 8) = *(const short8*)(tabst + tid * 8);
}

extern "C" __global__ __launch_bounds__(512, 2)
void schnet_tab(const int* __restrict__ z, const float* __restrict__ pos,
                const float* __restrict__ emb,
                const float* __restrict__ lin2_b, const float* __restrict__ lin_b,
                const float* __restrict__ out_b1, const float* __restrict__ out_w2,
                const float* __restrict__ out_b2,
                const unsigned short* __restrict__ ws,
                float* __restrict__ out)
{
    __shared__ __align__(16) unsigned char uni_s[ATP * XFP * 4];  // xf fp32 / tmp bf16 union
    __shared__ __align__(16) unsigned short hb_s[ATP * KP_W];
    __shared__ __align__(16) unsigned short aggb_s[ATP * KP_W];
    __shared__ __align__(16) unsigned short wbuf_s[SZ_BIG];
    __shared__ unsigned eoff_s[AT * AT];     // per-pair table byte offset (diag -> row 1023, T=0)
    __shared__ unsigned efpk_s[AT * AT];     // per-pair packed bf16x2 (1.0, f)
    __shared__ float pos_s[AT * 4];
    __shared__ float lb2_s[NT * HD], lb_s[NT * HD];
    __shared__ float ob1_s[64], ow2_s[64];
    __shared__ float red_s;
    float* xf_s = (float*)uni_s;
    unsigned short* tmp_s = (unsigned short*)uni_s;

    const int tid = threadIdx.x, m = blockIdx.x, base = m * AT;
    const int w = tid >> 6, lane = tid & 63, q = lane >> 4, lm = lane & 15;
    const int rn = w & 1, cn = w >> 1;   // node GEMMs: rows rn*16, cols cn*16 + c*64
    const int hl = lane >> 5, l32 = lane & 31, vlo = l32 * 16;

    g2l_async(ws + WS_LIN1(0), wbuf_s, SZ_BIG * 2, tid);

    // ---- init
    if (tid < AT * 3) pos_s[(tid / 3) * 4 + tid % 3] = pos[base * 3 + tid];
    if (tid < NT * HD) { lb2_s[tid] = lin2_b[tid]; lb_s[tid] = lin_b[tid]; }
    else if (tid < NT * HD + 64) ob1_s[tid - NT * HD] = out_b1[tid - NT * HD];
    else if (tid < NT * HD + 128) ow2_s[tid - NT * HD - 64] = out_w2[tid - NT * HD - 64];
    if (tid == 0) red_s = 0.f;
    float hreg[2][4];
#pragma unroll
    for (int c = 0; c < 2; ++c)
#pragma unroll
        for (int i = 0; i < 4; ++i) {
            int row = rn * 16 + q * 4 + i, col = cn * 16 + c * 64 + lm;
            float v = (row < AT) ? emb[z[base + row] * HD + col] : 0.f;
            hreg[c][i] = v;
            hb_s[row * KP_W + col] = f2bf(v);
        }
    for (int i = tid; i < 8 * HD; i += 512)
        aggb_s[(24 + (i >> 7)) * KP_W + (i & 127)] = 0;   // keep pad rows clean
    __syncthreads();
    // ---- per-pair (off, packed-f) precompute; diag -> table row 1023 (T==0 there), f=0
    const float INVH = (float)(NK - 1) / CUTOFF;
    for (int i = tid; i < AT * AT; i += 512) {
        int a = i / AT, s = i - a * AT;
        unsigned off; float f;
        if (a == s) { off = 1023u << 9; f = 0.f; }
        else {
            float dx = pos_s[s * 4 + 0] - pos_s[a * 4 + 0];
            float dy = pos_s[s * 4 + 1] - pos_s[a * 4 + 1];
            float dz = pos_s[s * 4 + 2] - pos_s[a * 4 + 2];
            float u = sqrtf(dx * dx + dy * dy + dz * dz) * INVH;
            int idx = (int)u;
            f = u - (float)idx;
            off = (unsigned)idx << 9;
        }
        eoff_s[i] = off;
        efpk_s[i] = 0x3F80u | ((unsigned)f2bf(f) << 16);
    }

    for (int t = 0; t < NT; ++t) {
        __syncthreads();   // B1: wbuf=lin1 ready, hb ready, eoff/efpk ready
        const char* tbase = (const char*)(ws + WS_TAB) + (size_t)t * (NK * 512);
        uint4 pkA[6], pkB[6];
        // step-0 table loads issued BEFORE the xf GEMM: latency hides under MFMA + B2 drain
        eissue(tbase, eoff_s, w, hl, vlo, 0, pkA);
        // ---- xf = h @ lin1 (fp32)
        {
            f32x4 acc[2] = {};
            gemm2<4>(&hb_s[(rn * 16 + lm) * KP_W], &wbuf_s[(cn * 16 + lm) * KP_W], q, acc);
#pragma unroll
            for (int c = 0; c < 2; ++c) {
                int col = cn * 16 + c * 64 + lm;
#pragma unroll
                for (int i = 0; i < 4; ++i)
                    xf_s[(rn * 16 + q * 4 + i) * XFP + col] = acc[c][i];
            }
        }
        __syncthreads();   // B2: xf visible, wbuf readers done
        g2l_async(ws + WS_LIN2(t), wbuf_s, SZ_BIG * 2, tid);
        // ---- edge aggregation: deep-2 pipeline, issue(k+1) before compute(k)
        {
            f32x4 ag[3] = {};
            eissue(tbase, eoff_s, w, hl, vlo, 4,  pkB);
            ecomp(xf_s, efpk_s, w, hl, l32, 0,  pkA, ag);
            eissue(tbase, eoff_s, w, hl, vlo, 8,  pkA);
            ecomp(xf_s, efpk_s, w, hl, l32, 4,  pkB, ag);
            eissue(tbase, eoff_s, w, hl, vlo, 12, pkB);
            ecomp(xf_s, efpk_s, w, hl, l32, 8,  pkA, ag);
            eissue(tbase, eoff_s, w, hl, vlo, 16, pkA);
            ecomp(xf_s, efpk_s, w, hl, l32, 12, pkB, ag);
            eissue(tbase, eoff_s, w, hl, vlo, 20, pkB);
            ecomp(xf_s, efpk_s, w, hl, l32, 16, pkA, ag);
            ecomp(xf_s, efpk_s, w, hl, l32, 20, pkB, ag);
            // merge s-parity halves (each lane then holds full sums for its 4 cols)
#pragma unroll
            for (int r = 0; r < 3; ++r)
#pragma unroll
                for (int i = 0; i < 4; ++i)
                    ag[r][i] += __shfl_xor(ag[r][i], 32);
            if (hl == 0) {
#pragma unroll
                for (int r = 0; r < 3; ++r) {
                    int a = w + 8 * r;
                    uint2 pkk;
                    pkk.x = ((unsigned)f2bf(ag[r][1]) << 16) | (unsigned)f2bf(ag[r][0]);
                    pkk.y = ((unsigned)f2bf(ag[r][3]) << 16) | (unsigned)f2bf(ag[r][2]);
                    *(uint2*)&aggb_s[a * KP_W + l32 * 4] = pkk;
                }
            }
        }
        __syncthreads();   // B3: aggb visible, wbuf=lin2 ready
        // lin(t) B-fragments -> registers (hidden under lin2 GEMM; used after B4)
        short8 lf[2][4];
        {
            const unsigned short* lwp = ws + WS_LIN(t);
#pragma unroll
            for (int c = 0; c < 2; ++c)
#pragma unroll
                for (int kt = 0; kt < 4; ++kt)
                    lf[c][kt] = *(const short8*)(lwp + (cn * 16 + c * 64 + lm) * KP_W + kt * 32 + q * 8);
        }
        // ---- tmp = ssp(agg @ lin2 + b)
        {
            f32x4 acc[2] = {};
            gemm2<4>(&aggb_s[(rn * 16 + lm) * KP_W], &wbuf_s[(cn * 16 + lm) * KP_W], q, acc);
#pragma unroll
            for (int c = 0; c < 2; ++c) {
                int col = cn * 16 + c * 64 + lm;
                float bb = lb2_s[t * HD + col];
#pragma unroll
                for (int i = 0; i < 4; ++i)
                    tmp_s[(rn * 16 + q * 4 + i) * KP_W + col] = f2bf(sspf(acc[c][i] + bb));
            }
        }
        __syncthreads();   // B4: tmp visible, wbuf readers done
        if (t < NT - 1) g2l_async(ws + WS_LIN1(t + 1), wbuf_s, SZ_BIG * 2, tid);
        else            g2l_async(ws + WS_OW1, wbuf_s, 64 * KP_W * 2, tid);
        // ---- h += tmp @ lin + b  (lin in registers)
        {
            f32x4 acc[2] = {};
            const unsigned short* A = &tmp_s[(rn * 16 + lm) * KP_W];
#pragma unroll
            for (int kt = 0; kt < 4; ++kt) {
                short8 a = *(const short8*)(A + kt * 32 + q * 8);
                acc[0] = mfma16(a, lf[0][kt], acc[0]);
                acc[1] = mfma16(a, lf[1][kt], acc[1]);
            }
#pragma unroll
            for (int c = 0; c < 2; ++c) {
                int col = cn * 16 + c * 64 + lm;
                float bb = lb_s[t * HD + col];
#pragma unroll
                for (int i = 0; i < 4; ++i) {
                    int row = rn * 16 + q * 4 + i;
                    float nh = hreg[c][i] + acc[c][i] + bb;
                    hreg[c][i] = nh;
                    hb_s[row * KP_W + col] = f2bf(nh);
                }
            }
        }
    }

    // ---- output head: sum_a ( ssp(h@ow1+b1) @ ow2 ) + 24*b2
    __syncthreads();   // hb ready, wbuf=ow1 ready
    {
        int rt = w & 1, co = w >> 1;       // C: 32x64 = 2x4 tiles, 8 waves, 1 frag each
        int j = co * 16 + lm;
        f32x4 acc = {};
        const unsigned short* A = &hb_s[(rt * 16 + lm) * KP_W];
        const unsigned short* B = &wbuf_s[j * KP_W];
#pragma unroll
        for (int kt = 0; kt < 4; ++kt)
            acc = mfma16(*(const short8*)(A + kt * 32 + q * 8),
                         *(const short8*)(B + kt * 32 + q * 8), acc);
        float sum = 0.f;
        float bb = ob1_s[j], wo = ow2_s[j];
#pragma unroll
        for (int i = 0; i < 4; ++i) {
            int row = rt * 16 + q * 4 + i;
            if (row < AT) sum += sspf(acc[i] + bb) * wo;
        }
        for (int off = 32; off > 0; off >>= 1) sum += __shfl_down(sum, off);
        if (lane == 0) atomicAdd(&red_s, sum);
    }
    __syncthreads();
    if (tid == 0) out[m] = red_s + (float)AT * out_b2[0];
}

extern "C" void kernel_launch(void* const* d_in, const int* in_sizes, int n_in,
                              void* d_out, int out_size, void* d_ws, size_t ws_size,
                              hipStream_t stream) {
    const int*   z    = (const int*)  d_in[0];
    const float* pos  = (const float*)d_in[1];
    const float* emb  = (const float*)d_in[4];
    const float* mw1  = (const float*)d_in[5];
    const float* mb1  = (const float*)d_in[6];
    const float* mw2  = (const float*)d_in[7];
    const float* mb2  = (const float*)d_in[8];
    const float* l1w  = (const float*)d_in[9];
    const float* l2w  = (const float*)d_in[10];
    const float* l2b  = (const float*)d_in[11];
    const float* lw   = (const float*)d_in[12];
    const float* lb   = (const float*)d_in[13];
    const float* ow1  = (const float*)d_in[14];
    const float* ob1  = (const float*)d_in[15];
    const float* ow2  = (const float*)d_in[16];
    const float* ob2  = (const float*)d_in[17];

    unsigned short* ws = (unsigned short*)d_ws;

    prep<<<dim3(424), dim3(256), 0, stream>>>(l1w, l2w, lw, ow1, mw1, mb1, mw2, mb2, ws);
    schnet_tab<<<dim3(1024), dim3(512), 0, stream>>>(
        z, pos, emb, l2b, lb, ob1, ow2, ob2, ws, (float*)d_out);
}

// Round 14
// 171.604 us; speedup vs baseline: 1.0489x; 1.0489x over previous
//
#include <hip/hip_runtime.h>
#include <math.h>

#define AT 24
#define ATP 32
#define HD 128
#define GD 50
#define NT 3
#define CUTOFF 10.0f
#define NK 1024        // table knots

#define KP_W 136       // padded K stride (bf16) for K=128
#define XFP 132        // xf fp32 row stride

#define SZ_BIG (128*KP_W)
#define WS_LIN1(t) ((t)*SZ_BIG)
#define WS_LIN2(t) ((3+(t))*SZ_BIG)
#define WS_LIN(t)  ((6+(t))*SZ_BIG)
#define WS_OW1     (9*SZ_BIG)
#define WS_TAB     (9*SZ_BIG + 64*KP_W)   // tab: [NT][NK][256] u16: per col-pair [T0,D0,T1,D1]

typedef __attribute__((ext_vector_type(8))) short short8;
typedef __attribute__((ext_vector_type(4))) float f32x4;
typedef __attribute__((ext_vector_type(2))) float f32x2;

__device__ __forceinline__ unsigned short f2bf(float x) {
    unsigned int u = __float_as_uint(x);
    return (unsigned short)((u + 0x7fffu + ((u >> 16) & 1u)) >> 16);
}
__device__ __forceinline__ float sspf(float x) {
    return fmaxf(x, 0.0f) + __logf(1.0f + __expf(-fabsf(x))) - 0.69314718055994531f;
}

// interp: td = (T lo16, D hi16) bf16 pair; fp = (1.0 lo16, f hi16) bf16 pair.
// result = T + f*D
#if __has_builtin(__builtin_amdgcn_fdot2_f32_bf16)
typedef __attribute__((ext_vector_type(2))) __bf16 bfv2;
__device__ __forceinline__ float dot2bf(unsigned td, unsigned fp) {
    return __builtin_amdgcn_fdot2_f32_bf16(
        __builtin_bit_cast(bfv2, td), __builtin_bit_cast(bfv2, fp), 0.0f, false);
}
#else
__device__ __forceinline__ float dot2bf(unsigned td, unsigned fp) {
    float t = __uint_as_float(td << 16);
    float d = __uint_as_float(td & 0xFFFF0000u);
    float f = __uint_as_float(fp & 0xFFFF0000u);
    return fmaf(f, d, t);
}
#endif

__device__ __forceinline__ f32x4 mfma16(short8 a, short8 b, f32x4 c) {
    return __builtin_amdgcn_mfma_f32_16x16x32_bf16(a, b, c, 0, 0, 0);
}

// load a wave's 2x4 B-fragments (cols cn*16 + c*64, K slices kt) straight from global (L2)
__device__ __forceinline__ void loadB(const unsigned short* __restrict__ Bp,
                                      int cn, int lm, int q, short8 (&bf)[2][4]) {
#pragma unroll
    for (int c = 0; c < 2; ++c)
#pragma unroll
        for (int kt = 0; kt < 4; ++kt)
            bf[c][kt] = *(const short8*)(Bp + (cn * 16 + c * 64 + lm) * KP_W + kt * 32 + q * 8);
}

// ---- merged prep: weight transpose (blocks 0..39) + interleaved (T,D) table ----
__global__ void __launch_bounds__(256) prep(
    const float* __restrict__ lin1_w, const float* __restrict__ lin2_w,
    const float* __restrict__ lin_w,  const float* __restrict__ out_w1,
    const float* __restrict__ mlp_w1, const float* __restrict__ mlp_b1,
    const float* __restrict__ mlp_w2, const float* __restrict__ mlp_b2,
    unsigned short* __restrict__ ws)
{
    int b = blockIdx.x, tid = threadIdx.x;
    if (b < 40) {
        const float* src; unsigned short* dst; int N, n0, rows;
        if (b < 36) {
            int mat = b >> 2, slice = b & 3;
            int grp = mat / 3, t = mat - grp * 3;
            const float* bases[3] = {lin1_w, lin2_w, lin_w};
            src = bases[grp] + t * HD * HD;
            dst = ws + (grp * 3 + t) * SZ_BIG;
            N = 128; n0 = slice * 32; rows = 32;
        } else {
            src = out_w1; dst = ws + WS_OW1; N = 64; n0 = (b - 36) * 16; rows = 16;
        }
        int nn = tid & 31, kk = tid >> 5;   // kk in [0,8) -> stride 8
        if (nn < rows) {
            for (int k = kk; k < KP_W; k += 8) {
                float v = (k < HD) ? src[k * N + n0 + nn] : 0.f;
                dst[(n0 + nn) * KP_W + k] = f2bf(v);
            }
        }
        return;
    }
    // ---- table blocks: block -> (t, 8-knot slab); 9 rows (1 overlap) for deltas.
    __shared__ __align__(16) float w2s[HD * HD];      // 64 KiB, staged via global_load_lds
    __shared__ __align__(16) float ea[9][52];
    __shared__ float pacc[4][5][128];                 // per-wave partial sums
    __shared__ __align__(16) unsigned short tabst[8 * 256];

    int b2 = b - 40;                 // [0, 384)
    int t = b2 >> 7, k0 = (b2 & 127) << 3;

    // stage w2[t] (65536 B) -> LDS: 256 thr x 16B = 4KB/iter, 16 iters
    {
        const char* gc = (const char*)(mlp_w2 + t * HD * HD) + tid * 16;
        char* lc = (char*)w2s + tid * 16;
#pragma unroll
        for (int ofs = 0; ofs < 65536; ofs += 4096)
            __builtin_amdgcn_global_load_lds(
                (const __attribute__((address_space(1))) unsigned int*)(gc + ofs),
                (__attribute__((address_space(3))) unsigned int*)(lc + ofs), 16, 0, 0);
    }

    const float h = CUTOFF / (NK - 1);
    const float STEP = CUTOFF / (GD - 1);
    const float COEFF = -0.5f / (STEP * STEP);
    for (int i = tid; i < 9 * GD; i += 256) {
        int rr = i / GD, g = i - rr * GD;
        int k = min(k0 + rr, NK - 1);
        float r = (float)k * h;
        float d = r - (float)g * STEP;
        ea[rr][g] = __expf(COEFF * d * d);
    }
    __syncthreads();   // ea visible; barrier drains vmcnt(0) -> w2s ready

    int j = tid & 127, kh = tid >> 7;            // kh half: rows kh*4 .. kh*4+4
    // ---- hid in registers: rows kh*4..kh*4+4 of column j
    float pre[5];
    float bb1 = mlp_b1[t * HD + j];
#pragma unroll
    for (int rr = 0; rr < 5; ++rr) pre[rr] = bb1;
    const float* w1p = mlp_w1 + t * GD * HD + j;
    for (int g0 = 0; g0 < 48; g0 += 4) {
        f32x4 e[5];
#pragma unroll
        for (int rr = 0; rr < 5; ++rr) e[rr] = *(const f32x4*)&ea[kh * 4 + rr][g0];
        float wv[4];
#pragma unroll
        for (int gg = 0; gg < 4; ++gg) wv[gg] = w1p[(g0 + gg) * HD];
#pragma unroll
        for (int gg = 0; gg < 4; ++gg)
#pragma unroll
            for (int rr = 0; rr < 5; ++rr)
                pre[rr] = fmaf(e[rr][gg], wv[gg], pre[rr]);
    }
#pragma unroll
    for (int g = 48; g < GD; ++g) {
        float wv = w1p[g * HD];
#pragma unroll
        for (int rr = 0; rr < 5; ++rr)
            pre[rr] = fmaf(ea[kh * 4 + rr][g], wv, pre[rr]);
    }
#pragma unroll
    for (int rr = 0; rr < 5; ++rr) pre[rr] = sspf(pre[rr]);

    // ---- u-contraction: wave wv_ owns rows (wv_>>1)*4..+4, u-range (wv_&1)*64..+64.
    {
        int wv_ = tid >> 6, l = tid & 63;
        int ubase = (wv_ & 1) << 6;
        float a0[5], a1[5];
#pragma unroll
        for (int rr = 0; rr < 5; ++rr) { a0[rr] = 0.f; a1[rr] = 0.f; }
#pragma unroll 8
        for (int step = 0; step < 64; ++step) {
            int uu = ubase + step;
            float wa = w2s[uu * HD + l];
            float wb = w2s[uu * HD + l + 64];
#pragma unroll
            for (int rr = 0; rr < 5; ++rr) {
                float hv = __uint_as_float(
                    __builtin_amdgcn_readlane(__float_as_uint(pre[rr]), step));
                a0[rr] = fmaf(hv, wa, a0[rr]);
                a1[rr] = fmaf(hv, wb, a1[rr]);
            }
        }
#pragma unroll
        for (int rr = 0; rr < 5; ++rr) {
            pacc[wv_][rr][l] = a0[rr];
            pacc[wv_][rr][l + 64] = a1[rr];
        }
    }
    __syncthreads();
    // ---- finalize in original writer layout: thread (kh, j), rows kh*4+rr
    float bb2 = mlp_b2[t * HD + j];
    float Tv[5];
#pragma unroll
    for (int rr = 0; rr < 5; ++rr) {
        float s = pacc[2 * kh][rr][j] + pacc[2 * kh + 1][rr][j] + bb2;
        int k = min(k0 + kh * 4 + rr, NK - 1);
        float r = (float)k * h;
        Tv[rr] = s * 0.5f * (__cosf(r * 0.31415926535897931f) + 1.0f);
    }
#pragma unroll
    for (int rr = 0; rr < 4; ++rr) {
        int kr = kh * 4 + rr;
        int ofs = kr * 256 + (j >> 1) * 4 + (j & 1) * 2;   // [T,D] interleaved per column
        tabst[ofs]     = f2bf(Tv[rr]);
        tabst[ofs + 1] = f2bf(Tv[rr + 1] - Tv[rr]);
    }
    __syncthreads();
    // coalesced write-out: 256 thr x 16B = 4KB slab
    unsigned short* tb = ws + WS_TAB + (size_t)t * NK * 256 + k0 * 256;
    *(short8*)(tb + tid * 8) = *(const short8*)(tabst + tid * 8);
}

extern "C" __global__ __launch_bounds__(512, 4)
void schnet_tab(const int* __restrict__ z, const float* __restrict__ pos,
                const float* __restrict__ emb,
                const float* __restrict__ lin2_b, const float* __restrict__ lin_b,
                const float* __restrict__ out_b1, const float* __restrict__ out_w2,
                const float* __restrict__ out_b2,
                const unsigned short* __restrict__ ws,
                float* __restrict__ out)
{
    // no wbuf staging: LDS ~39.3 KB -> 4 blocks/CU; B-fragments direct from L2-resident ws
    __shared__ __align__(16) unsigned char uni_s[ATP * XFP * 4];  // xf fp32 / tmp bf16 union
    __shared__ __align__(16) unsigned short hb_s[ATP * KP_W];
    __shared__ __align__(16) unsigned short aggb_s[ATP * KP_W];
    __shared__ unsigned eoff_s[AT * AT];     // per-pair table byte offset (diag -> row 1023, T=0)
    __shared__ unsigned efpk_s[AT * AT];     // per-pair packed bf16x2 (1.0, f)
    __shared__ float pos_s[AT * 4];
    __shared__ float red_s;
    float* xf_s = (float*)uni_s;
    unsigned short* tmp_s = (unsigned short*)uni_s;

    const int tid = threadIdx.x, m = blockIdx.x, base = m * AT;
    const int w = tid >> 6, lane = tid & 63, q = lane >> 4, lm = lane & 15;
    const int rn = w & 1, cn = w >> 1;   // node GEMMs: rows rn*16, cols cn*16 + c*64
    const int hl = lane >> 5, l32 = lane & 31, vlo = l32 * 16;

    // ---- init
    if (tid < AT * 3) pos_s[(tid / 3) * 4 + tid % 3] = pos[base * 3 + tid];
    if (tid == 0) red_s = 0.f;
    float hreg[2][4];
#pragma unroll
    for (int c = 0; c < 2; ++c)
#pragma unroll
        for (int i = 0; i < 4; ++i) {
            int row = rn * 16 + q * 4 + i, col = cn * 16 + c * 64 + lm;
            float v = (row < AT) ? emb[z[base + row] * HD + col] : 0.f;
            hreg[c][i] = v;
            hb_s[row * KP_W + col] = f2bf(v);
        }
    for (int i = tid; i < 8 * HD; i += 512)
        aggb_s[(24 + (i >> 7)) * KP_W + (i & 127)] = 0;   // keep pad rows clean
    __syncthreads();
    // ---- per-pair (off, packed-f) precompute; diag -> table row 1023 (T==0 there), f=0
    const float INVH = (float)(NK - 1) / CUTOFF;
    for (int i = tid; i < AT * AT; i += 512) {
        int a = i / AT, s = i - a * AT;
        unsigned off; float f;
        if (a == s) { off = 1023u << 9; f = 0.f; }
        else {
            float dx = pos_s[s * 4 + 0] - pos_s[a * 4 + 0];
            float dy = pos_s[s * 4 + 1] - pos_s[a * 4 + 1];
            float dz = pos_s[s * 4 + 2] - pos_s[a * 4 + 2];
            float u = sqrtf(dx * dx + dy * dy + dz * dz) * INVH;
            int idx = (int)u;
            f = u - (float)idx;
            off = (unsigned)idx << 9;
        }
        eoff_s[i] = off;
        efpk_s[i] = 0x3F80u | ((unsigned)f2bf(f) << 16);
    }

    for (int t = 0; t < NT; ++t) {
        // xf-GEMM B-fragments: depend only on constant ws -> issue BEFORE the barrier,
        // latency hides under the barrier wait
        short8 bf1[2][4];
        loadB(ws + WS_LIN1(t), cn, lm, q, bf1);
        __syncthreads();   // B1: hb ready, eoff/efpk ready, prior tmp readers done
        // ---- xf = h @ lin1 (fp32)
        {
            f32x4 acc[2] = {};
            const unsigned short* A = &hb_s[(rn * 16 + lm) * KP_W];
#pragma unroll
            for (int kt = 0; kt < 4; ++kt) {
                short8 a = *(const short8*)(A + kt * 32 + q * 8);
                acc[0] = mfma16(a, bf1[0][kt], acc[0]);
                acc[1] = mfma16(a, bf1[1][kt], acc[1]);
            }
#pragma unroll
            for (int c = 0; c < 2; ++c) {
                int col = cn * 16 + c * 64 + lm;
#pragma unroll
                for (int i = 0; i < 4; ++i)
                    xf_s[(rn * 16 + q * 4 + i) * XFP + col] = acc[c][i];
            }
        }
        __syncthreads();   // B2: xf visible
        // ---- edge aggregation: dst a = w + 8r; half-wave s-parity split, 16B table loads
        {
            const char* tbase = (const char*)(ws + WS_TAB) + (size_t)t * (NK * 512);
            f32x4 ag[3] = {};
#pragma unroll 1
            for (int s0 = 0; s0 < AT; s0 += 6) {
                uint4 pk[3][3]; unsigned fp[3][3]; f32x4 xv[3];
#pragma unroll
                for (int pp = 0; pp < 3; ++pp) {
                    int s = s0 + 2 * pp + hl;
                    xv[pp] = *(const f32x4*)&xf_s[s * XFP + l32 * 4];
#pragma unroll
                    for (int r = 0; r < 3; ++r) {
                        int a = w + 8 * r;
                        unsigned off = eoff_s[a * AT + s];
                        fp[r][pp] = efpk_s[a * AT + s];
                        pk[r][pp] = *(const uint4*)(tbase + (off + vlo));
                    }
                }
#pragma unroll
                for (int pp = 0; pp < 3; ++pp) {
#pragma unroll
                    for (int r = 0; r < 3; ++r) {
                        uint4 p = pk[r][pp];
                        unsigned f = fp[r][pp];
                        ag[r][0] = fmaf(dot2bf(p.x, f), xv[pp][0], ag[r][0]);
                        ag[r][1] = fmaf(dot2bf(p.y, f), xv[pp][1], ag[r][1]);
                        ag[r][2] = fmaf(dot2bf(p.z, f), xv[pp][2], ag[r][2]);
                        ag[r][3] = fmaf(dot2bf(p.w, f), xv[pp][3], ag[r][3]);
                    }
                }
            }
            // merge s-parity halves (each lane then holds full sums for its 4 cols)
#pragma unroll
            for (int r = 0; r < 3; ++r)
#pragma unroll
                for (int i = 0; i < 4; ++i)
                    ag[r][i] += __shfl_xor(ag[r][i], 32);
            if (hl == 0) {
#pragma unroll
                for (int r = 0; r < 3; ++r) {
                    int a = w + 8 * r;
                    uint2 pkk;
                    pkk.x = ((unsigned)f2bf(ag[r][1]) << 16) | (unsigned)f2bf(ag[r][0]);
                    pkk.y = ((unsigned)f2bf(ag[r][3]) << 16) | (unsigned)f2bf(ag[r][2]);
                    *(uint2*)&aggb_s[a * KP_W + l32 * 4] = pkk;
                }
            }
        }
        __syncthreads();   // B3: aggb visible, xf readers done (uni_s reusable as tmp)
        // lin(t) B-fragments -> registers (latency hides under lin2 GEMM; used after B4)
        short8 lf[2][4];
        loadB(ws + WS_LIN(t), cn, lm, q, lf);
        // ---- tmp = ssp(agg @ lin2 + b)
        {
            short8 bf2[2][4];
            loadB(ws + WS_LIN2(t), cn, lm, q, bf2);
            f32x4 acc[2] = {};
            const unsigned short* A = &aggb_s[(rn * 16 + lm) * KP_W];
#pragma unroll
            for (int kt = 0; kt < 4; ++kt) {
                short8 a = *(const short8*)(A + kt * 32 + q * 8);
                acc[0] = mfma16(a, bf2[0][kt], acc[0]);
                acc[1] = mfma16(a, bf2[1][kt], acc[1]);
            }
#pragma unroll
            for (int c = 0; c < 2; ++c) {
                int col = cn * 16 + c * 64 + lm;
                float bb = lin2_b[t * HD + col];
#pragma unroll
                for (int i = 0; i < 4; ++i)
                    tmp_s[(rn * 16 + q * 4 + i) * KP_W + col] = f2bf(sspf(acc[c][i] + bb));
            }
        }
        __syncthreads();   // B4: tmp visible
        // ---- h += tmp @ lin + b  (lin in registers)
        {
            f32x4 acc[2] = {};
            const unsigned short* A = &tmp_s[(rn * 16 + lm) * KP_W];
#pragma unroll
            for (int kt = 0; kt < 4; ++kt) {
                short8 a = *(const short8*)(A + kt * 32 + q * 8);
                acc[0] = mfma16(a, lf[0][kt], acc[0]);
                acc[1] = mfma16(a, lf[1][kt], acc[1]);
            }
#pragma unroll
            for (int c = 0; c < 2; ++c) {
                int col = cn * 16 + c * 64 + lm;
                float bb = lin_b[t * HD + col];
#pragma unroll
                for (int i = 0; i < 4; ++i) {
                    int row = rn * 16 + q * 4 + i;
                    float nh = hreg[c][i] + acc[c][i] + bb;
                    hreg[c][i] = nh;
                    hb_s[row * KP_W + col] = f2bf(nh);
                }
            }
        }
    }

    // ---- output head: sum_a ( ssp(h@ow1+b1) @ ow2 ) + 24*b2
    __syncthreads();   // hb ready
    {
        int rt = w & 1, co = w >> 1;       // C: 32x64 = 2x4 tiles, 8 waves, 1 frag each
        int j = co * 16 + lm;
        short8 bh[4];
        const unsigned short* Bp = ws + WS_OW1 + j * KP_W;
#pragma unroll
        for (int kt = 0; kt < 4; ++kt)
            bh[kt] = *(const short8*)(Bp + kt * 32 + q * 8);
        f32x4 acc = {};
        const unsigned short* A = &hb_s[(rt * 16 + lm) * KP_W];
#pragma unroll
        for (int kt = 0; kt < 4; ++kt)
            acc = mfma16(*(const short8*)(A + kt * 32 + q * 8), bh[kt], acc);
        float sum = 0.f;
        float bb = out_b1[j], wo = out_w2[j];
#pragma unroll
        for (int i = 0; i < 4; ++i) {
            int row = rt * 16 + q * 4 + i;
            if (row < AT) sum += sspf(acc[i] + bb) * wo;
        }
        for (int off = 32; off > 0; off >>= 1) sum += __shfl_down(sum, off);
        if (lane == 0) atomicAdd(&red_s, sum);
    }
    __syncthreads();
    if (tid == 0) out[m] = red_s + (float)AT * out_b2[0];
}

extern "C" void kernel_launch(void* const* d_in, const int* in_sizes, int n_in,
                              void* d_out, int out_size, void* d_ws, size_t ws_size,
                              hipStream_t stream) {
    const int*   z    = (const int*)  d_in[0];
    const float* pos  = (const float*)d_in[1];
    const float* emb  = (const float*)d_in[4];
    const float* mw1  = (const float*)d_in[5];
    const float* mb1  = (const float*)d_in[6];
    const float* mw2  = (const float*)d_in[7];
    const float* mb2  = (const float*)d_in[8];
    const float* l1w  = (const float*)d_in[9];
    const float* l2w  = (const float*)d_in[10];
    const float* l2b  = (const float*)d_in[11];
    const float* lw   = (const float*)d_in[12];
    const float* lb   = (const float*)d_in[13];
    const float* ow1  = (const float*)d_in[14];
    const float* ob1  = (const float*)d_in[15];
    const float* ow2  = (const float*)d_in[16];
    const float* ob2  = (const float*)d_in[17];

    unsigned short* ws = (unsigned short*)d_ws;

    prep<<<dim3(424), dim3(256), 0, stream>>>(l1w, l2w, lw, ow1, mw1, mb1, mw2, mb2, ws);
    schnet_tab<<<dim3(1024), dim3(512), 0, stream>>>(
        z, pos, emb, l2b, lb, ob1, ow2, ob2, ws, (float*)d_out);
}

// Round 15
// 163.563 us; speedup vs baseline: 1.1005x; 1.0492x over previous
//
#include <hip/hip_runtime.h>
#include <math.h>

#define AT 24
#define ATP 32
#define HD 128
#define GD 50
#define NT 3
#define CUTOFF 10.0f
#define NK 1024        // table knots

#define KP_W 136       // padded K stride (bf16) for K=128
#define XFP 132        // xf fp32 row stride

#define SZ_BIG (128*KP_W)
#define WS_LIN1(t) ((t)*SZ_BIG)
#define WS_LIN2(t) ((3+(t))*SZ_BIG)
#define WS_LIN(t)  ((6+(t))*SZ_BIG)
#define WS_OW1     (9*SZ_BIG)
#define WS_TAB     (9*SZ_BIG + 64*KP_W)   // tab: [NT][NK][256] u16: per col-pair [T0,D0,T1,D1]

typedef __attribute__((ext_vector_type(8))) short short8;
typedef __attribute__((ext_vector_type(4))) float f32x4;
typedef __attribute__((ext_vector_type(2))) float f32x2;

__device__ __forceinline__ unsigned short f2bf(float x) {
    unsigned int u = __float_as_uint(x);
    return (unsigned short)((u + 0x7fffu + ((u >> 16) & 1u)) >> 16);
}
__device__ __forceinline__ float sspf(float x) {
    return fmaxf(x, 0.0f) + __logf(1.0f + __expf(-fabsf(x))) - 0.69314718055994531f;
}

// interp: td = (T lo16, D hi16) bf16 pair; fp = (1.0 lo16, f hi16) bf16 pair.
// result = T + f*D
#if __has_builtin(__builtin_amdgcn_fdot2_f32_bf16)
typedef __attribute__((ext_vector_type(2))) __bf16 bfv2;
__device__ __forceinline__ float dot2bf(unsigned td, unsigned fp) {
    return __builtin_amdgcn_fdot2_f32_bf16(
        __builtin_bit_cast(bfv2, td), __builtin_bit_cast(bfv2, fp), 0.0f, false);
}
#else
__device__ __forceinline__ float dot2bf(unsigned td, unsigned fp) {
    float t = __uint_as_float(td << 16);
    float d = __uint_as_float(td & 0xFFFF0000u);
    float f = __uint_as_float(fp & 0xFFFF0000u);
    return fmaf(f, d, t);
}
#endif

// async global->LDS; bytes multiple of 1024; 512 threads
__device__ __forceinline__ void g2l_async(const void* g, void* l, int bytes, int tid) {
    int w = tid >> 6, lane = tid & 63;
    const char* gc = (const char*)g + lane * 16;
    char* lc = (char*)l + lane * 16;
    for (int ofs = w * 1024; ofs < bytes; ofs += 8192) {
        __builtin_amdgcn_global_load_lds(
            (const __attribute__((address_space(1))) unsigned int*)(gc + ofs),
            (__attribute__((address_space(3))) unsigned int*)(lc + ofs), 16, 0, 0);
    }
}

__device__ __forceinline__ f32x4 mfma16(short8 a, short8 b, f32x4 c) {
    return __builtin_amdgcn_mfma_f32_16x16x32_bf16(a, b, c, 0, 0, 0);
}

// 16x(2x16) GEMM from LDS: A rows rt*16, B cols cn*16 + c*64
template<int NKT>
__device__ __forceinline__ void gemm2(const unsigned short* A, const unsigned short* B,
                                      int q, f32x4* acc)
{
#pragma unroll
    for (int kt = 0; kt < NKT; ++kt) {
        short8 a  = *(const short8*)(A + kt * 32 + q * 8);
        short8 b0 = *(const short8*)(B + kt * 32 + q * 8);
        short8 b1 = *(const short8*)(B + 64 * KP_W + kt * 32 + q * 8);
        acc[0] = mfma16(a, b0, acc[0]);
        acc[1] = mfma16(a, b1, acc[1]);
    }
}

// ---- merged prep: weight transpose (blocks 0..39) + interleaved (T,D) table ----
__global__ void __launch_bounds__(256) prep(
    const float* __restrict__ lin1_w, const float* __restrict__ lin2_w,
    const float* __restrict__ lin_w,  const float* __restrict__ out_w1,
    const float* __restrict__ mlp_w1, const float* __restrict__ mlp_b1,
    const float* __restrict__ mlp_w2, const float* __restrict__ mlp_b2,
    unsigned short* __restrict__ ws)
{
    int b = blockIdx.x, tid = threadIdx.x;
    if (b < 40) {
        const float* src; unsigned short* dst; int N, n0, rows;
        if (b < 36) {
            int mat = b >> 2, slice = b & 3;
            int grp = mat / 3, t = mat - grp * 3;
            const float* bases[3] = {lin1_w, lin2_w, lin_w};
            src = bases[grp] + t * HD * HD;
            dst = ws + (grp * 3 + t) * SZ_BIG;
            N = 128; n0 = slice * 32; rows = 32;
        } else {
            src = out_w1; dst = ws + WS_OW1; N = 64; n0 = (b - 36) * 16; rows = 16;
        }
        int nn = tid & 31, kk = tid >> 5;   // kk in [0,8) -> stride 8
        if (nn < rows) {
            for (int k = kk; k < KP_W; k += 8) {
                float v = (k < HD) ? src[k * N + n0 + nn] : 0.f;
                dst[(n0 + nn) * KP_W + k] = f2bf(v);
            }
        }
        return;
    }
    // ---- table blocks: block -> (t, 8-knot slab); 9 rows (1 overlap) for deltas.
    __shared__ __align__(16) float w2s[HD * HD];      // 64 KiB, staged via global_load_lds
    __shared__ __align__(16) float ea[9][52];
    __shared__ float pacc[4][5][128];                 // per-wave partial sums
    __shared__ __align__(16) unsigned short tabst[8 * 256];

    int b2 = b - 40;                 // [0, 384)
    int t = b2 >> 7, k0 = (b2 & 127) << 3;

    // stage w2[t] (65536 B) -> LDS: 256 thr x 16B = 4KB/iter, 16 iters
    {
        const char* gc = (const char*)(mlp_w2 + t * HD * HD) + tid * 16;
        char* lc = (char*)w2s + tid * 16;
#pragma unroll
        for (int ofs = 0; ofs < 65536; ofs += 4096)
            __builtin_amdgcn_global_load_lds(
                (const __attribute__((address_space(1))) unsigned int*)(gc + ofs),
                (__attribute__((address_space(3))) unsigned int*)(lc + ofs), 16, 0, 0);
    }

    const float h = CUTOFF / (NK - 1);
    const float STEP = CUTOFF / (GD - 1);
    const float COEFF = -0.5f / (STEP * STEP);
    for (int i = tid; i < 9 * GD; i += 256) {
        int rr = i / GD, g = i - rr * GD;
        int k = min(k0 + rr, NK - 1);
        float r = (float)k * h;
        float d = r - (float)g * STEP;
        ea[rr][g] = __expf(COEFF * d * d);
    }
    __syncthreads();   // ea visible; barrier drains vmcnt(0) -> w2s ready

    int j = tid & 127, kh = tid >> 7;            // kh half: rows kh*4 .. kh*4+4
    // ---- hid in registers: rows kh*4..kh*4+4 of column j
    float pre[5];
    float bb1 = mlp_b1[t * HD + j];
#pragma unroll
    for (int rr = 0; rr < 5; ++rr) pre[rr] = bb1;
    const float* w1p = mlp_w1 + t * GD * HD + j;
    for (int g0 = 0; g0 < 48; g0 += 4) {
        f32x4 e[5];
#pragma unroll
        for (int rr = 0; rr < 5; ++rr) e[rr] = *(const f32x4*)&ea[kh * 4 + rr][g0];
        float wv[4];
#pragma unroll
        for (int gg = 0; gg < 4; ++gg) wv[gg] = w1p[(g0 + gg) * HD];
#pragma unroll
        for (int gg = 0; gg < 4; ++gg)
#pragma unroll
            for (int rr = 0; rr < 5; ++rr)
                pre[rr] = fmaf(e[rr][gg], wv[gg], pre[rr]);
    }
#pragma unroll
    for (int g = 48; g < GD; ++g) {
        float wv = w1p[g * HD];
#pragma unroll
        for (int rr = 0; rr < 5; ++rr)
            pre[rr] = fmaf(ea[kh * 4 + rr][g], wv, pre[rr]);
    }
#pragma unroll
    for (int rr = 0; rr < 5; ++rr) pre[rr] = sspf(pre[rr]);

    // ---- u-contraction: wave wv_ owns rows (wv_>>1)*4..+4, u-range (wv_&1)*64..+64.
    {
        int wv_ = tid >> 6, l = tid & 63;
        int ubase = (wv_ & 1) << 6;
        float a0[5], a1[5];
#pragma unroll
        for (int rr = 0; rr < 5; ++rr) { a0[rr] = 0.f; a1[rr] = 0.f; }
#pragma unroll 8
        for (int step = 0; step < 64; ++step) {
            int uu = ubase + step;
            float wa = w2s[uu * HD + l];
            float wb = w2s[uu * HD + l + 64];
#pragma unroll
            for (int rr = 0; rr < 5; ++rr) {
                float hv = __uint_as_float(
                    __builtin_amdgcn_readlane(__float_as_uint(pre[rr]), step));
                a0[rr] = fmaf(hv, wa, a0[rr]);
                a1[rr] = fmaf(hv, wb, a1[rr]);
            }
        }
#pragma unroll
        for (int rr = 0; rr < 5; ++rr) {
            pacc[wv_][rr][l] = a0[rr];
            pacc[wv_][rr][l + 64] = a1[rr];
        }
    }
    __syncthreads();
    // ---- finalize in original writer layout: thread (kh, j), rows kh*4+rr
    float bb2 = mlp_b2[t * HD + j];
    float Tv[5];
#pragma unroll
    for (int rr = 0; rr < 5; ++rr) {
        float s = pacc[2 * kh][rr][j] + pacc[2 * kh + 1][rr][j] + bb2;
        int k = min(k0 + kh * 4 + rr, NK - 1);
        float r = (float)k * h;
        Tv[rr] = s * 0.5f * (__cosf(r * 0.31415926535897931f) + 1.0f);
    }
#pragma unroll
    for (int rr = 0; rr < 4; ++rr) {
        int kr = kh * 4 + rr;
        int ofs = kr * 256 + (j >> 1) * 4 + (j & 1) * 2;   // [T,D] interleaved per column
        tabst[ofs]     = f2bf(Tv[rr]);
        tabst[ofs + 1] = f2bf(Tv[rr + 1] - Tv[rr]);
    }
    __syncthreads();
    // coalesced write-out: 256 thr x 16B = 4KB slab
    unsigned short* tb = ws + WS_TAB + (size_t)t * NK * 256 + k0 * 256;
    *(short8*)(tb + tid * 8) = *(const short8*)(tabst + tid * 8);
}

extern "C" __global__ __launch_bounds__(512, 4)
void schnet_tab(const int* __restrict__ z, const float* __restrict__ pos,
                const float* __restrict__ emb,
                const float* __restrict__ lin2_b, const float* __restrict__ lin_b,
                const float* __restrict__ out_b1, const float* __restrict__ out_w2,
                const float* __restrict__ out_b2,
                const unsigned short* __restrict__ ws,
                float* __restrict__ out)
{
    __shared__ __align__(16) unsigned char uni_s[ATP * XFP * 4];  // xf fp32 / tmp bf16 union
    __shared__ __align__(16) unsigned short hb_s[ATP * KP_W];
    __shared__ __align__(16) unsigned short aggb_s[ATP * KP_W];
    __shared__ __align__(16) unsigned short wbuf_s[SZ_BIG];
    __shared__ unsigned eoff_s[AT * AT];     // per-pair table byte offset (diag -> row 1023, T=0)
    __shared__ unsigned efpk_s[AT * AT];     // per-pair packed bf16x2 (1.0, f)
    __shared__ float pos_s[AT * 4];
    __shared__ float lb2_s[NT * HD], lb_s[NT * HD];
    __shared__ float ob1_s[64], ow2_s[64];
    __shared__ float red_s;
    float* xf_s = (float*)uni_s;
    unsigned short* tmp_s = (unsigned short*)uni_s;

    const int tid = threadIdx.x, m = blockIdx.x, base = m * AT;
    const int w = tid >> 6, lane = tid & 63, q = lane >> 4, lm = lane & 15;
    const int rn = w & 1, cn = w >> 1;   // node GEMMs: rows rn*16, cols cn*16 + c*64

    g2l_async(ws + WS_LIN1(0), wbuf_s, SZ_BIG * 2, tid);

    // ---- init
    if (tid < AT * 3) pos_s[(tid / 3) * 4 + tid % 3] = pos[base * 3 + tid];
    if (tid < NT * HD) { lb2_s[tid] = lin2_b[tid]; lb_s[tid] = lin_b[tid]; }
    else if (tid < NT * HD + 64) ob1_s[tid - NT * HD] = out_b1[tid - NT * HD];
    else if (tid < NT * HD + 128) ow2_s[tid - NT * HD - 64] = out_w2[tid - NT * HD - 64];
    if (tid == 0) red_s = 0.f;
    float hreg[2][4];
#pragma unroll
    for (int c = 0; c < 2; ++c)
#pragma unroll
        for (int i = 0; i < 4; ++i) {
            int row = rn * 16 + q * 4 + i, col = cn * 16 + c * 64 + lm;
            float v = (row < AT) ? emb[z[base + row] * HD + col] : 0.f;
            hreg[c][i] = v;
            hb_s[row * KP_W + col] = f2bf(v);
        }
    for (int i = tid; i < 8 * HD; i += 512)
        aggb_s[(24 + (i >> 7)) * KP_W + (i & 127)] = 0;   // keep pad rows clean
    __syncthreads();
    // ---- per-pair (off, packed-f) precompute; diag -> table row 1023 (T==0 there), f=0
    const float INVH = (float)(NK - 1) / CUTOFF;
    for (int i = tid; i < AT * AT; i += 512) {
        int a = i / AT, s = i - a * AT;
        unsigned off; float f;
        if (a == s) { off = 1023u << 9; f = 0.f; }
        else {
            float dx = pos_s[s * 4 + 0] - pos_s[a * 4 + 0];
            float dy = pos_s[s * 4 + 1] - pos_s[a * 4 + 1];
            float dz = pos_s[s * 4 + 2] - pos_s[a * 4 + 2];
            float u = sqrtf(dx * dx + dy * dy + dz * dz) * INVH;
            int idx = (int)u;
            f = u - (float)idx;
            off = (unsigned)idx << 9;
        }
        eoff_s[i] = off;
        efpk_s[i] = 0x3F80u | ((unsigned)f2bf(f) << 16);
    }

    for (int t = 0; t < NT; ++t) {
        __syncthreads();   // B1: wbuf=lin1 ready, hb ready, eoff/efpk ready
        // ---- xf = h @ lin1 (fp32)
        {
            f32x4 acc[2] = {};
            gemm2<4>(&hb_s[(rn * 16 + lm) * KP_W], &wbuf_s[(cn * 16 + lm) * KP_W], q, acc);
#pragma unroll
            for (int c = 0; c < 2; ++c) {
                int col = cn * 16 + c * 64 + lm;
#pragma unroll
                for (int i = 0; i < 4; ++i)
                    xf_s[(rn * 16 + q * 4 + i) * XFP + col] = acc[c][i];
            }
        }
        __syncthreads();   // B2: xf visible, wbuf readers done
        g2l_async(ws + WS_LIN2(t), wbuf_s, SZ_BIG * 2, tid);
        // ---- edge aggregation: dst a = w + 8r; half-wave s-parity split, 16B table loads
        {
            const char* tbase = (const char*)(ws + WS_TAB) + (size_t)t * (NK * 512);
            const int hl = lane >> 5, l32 = lane & 31;
            const int vlo = l32 * 16;
            f32x4 ag[3] = {};
#pragma unroll 1
            for (int s0 = 0; s0 < AT; s0 += 6) {
                uint4 pk[3][3]; unsigned fp[3][3]; f32x4 xv[3];
#pragma unroll
                for (int pp = 0; pp < 3; ++pp) {
                    int s = s0 + 2 * pp + hl;
                    xv[pp] = *(const f32x4*)&xf_s[s * XFP + l32 * 4];
#pragma unroll
                    for (int r = 0; r < 3; ++r) {
                        int a = w + 8 * r;
                        unsigned off = eoff_s[a * AT + s];
                        fp[r][pp] = efpk_s[a * AT + s];
                        pk[r][pp] = *(const uint4*)(tbase + (off + vlo));
                    }
                }
#pragma unroll
                for (int pp = 0; pp < 3; ++pp) {
#pragma unroll
                    for (int r = 0; r < 3; ++r) {
                        uint4 p = pk[r][pp];
                        unsigned f = fp[r][pp];
                        ag[r][0] = fmaf(dot2bf(p.x, f), xv[pp][0], ag[r][0]);
                        ag[r][1] = fmaf(dot2bf(p.y, f), xv[pp][1], ag[r][1]);
                        ag[r][2] = fmaf(dot2bf(p.z, f), xv[pp][2], ag[r][2]);
                        ag[r][3] = fmaf(dot2bf(p.w, f), xv[pp][3], ag[r][3]);
                    }
                }
            }
            // merge s-parity halves (each lane then holds full sums for its 4 cols)
#pragma unroll
            for (int r = 0; r < 3; ++r)
#pragma unroll
                for (int i = 0; i < 4; ++i)
                    ag[r][i] += __shfl_xor(ag[r][i], 32);
            if (hl == 0) {
#pragma unroll
                for (int r = 0; r < 3; ++r) {
                    int a = w + 8 * r;
                    uint2 pkk;
                    pkk.x = ((unsigned)f2bf(ag[r][1]) << 16) | (unsigned)f2bf(ag[r][0]);
                    pkk.y = ((unsigned)f2bf(ag[r][3]) << 16) | (unsigned)f2bf(ag[r][2]);
                    *(uint2*)&aggb_s[a * KP_W + l32 * 4] = pkk;
                }
            }
        }
        __syncthreads();   // B3: aggb visible, wbuf=lin2 ready
        // lin(t) B-fragments -> registers (hidden under lin2 GEMM; used after B4)
        short8 lf[2][4];
        {
            const unsigned short* lwp = ws + WS_LIN(t);
#pragma unroll
            for (int c = 0; c < 2; ++c)
#pragma unroll
                for (int kt = 0; kt < 4; ++kt)
                    lf[c][kt] = *(const short8*)(lwp + (cn * 16 + c * 64 + lm) * KP_W + kt * 32 + q * 8);
        }
        // ---- tmp = ssp(agg @ lin2 + b)
        {
            f32x4 acc[2] = {};
            gemm2<4>(&aggb_s[(rn * 16 + lm) * KP_W], &wbuf_s[(cn * 16 + lm) * KP_W], q, acc);
#pragma unroll
            for (int c = 0; c < 2; ++c) {
                int col = cn * 16 + c * 64 + lm;
                float bb = lb2_s[t * HD + col];
#pragma unroll
                for (int i = 0; i < 4; ++i)
                    tmp_s[(rn * 16 + q * 4 + i) * KP_W + col] = f2bf(sspf(acc[c][i] + bb));
            }
        }
        __syncthreads();   // B4: tmp visible, wbuf readers done
        if (t < NT - 1) g2l_async(ws + WS_LIN1(t + 1), wbuf_s, SZ_BIG * 2, tid);
        else            g2l_async(ws + WS_OW1, wbuf_s, 64 * KP_W * 2, tid);
        // ---- h += tmp @ lin + b  (lin in registers)
        {
            f32x4 acc[2] = {};
            const unsigned short* A = &tmp_s[(rn * 16 + lm) * KP_W];
#pragma unroll
            for (int kt = 0; kt < 4; ++kt) {
                short8 a = *(const short8*)(A + kt * 32 + q * 8);
                acc[0] = mfma16(a, lf[0][kt], acc[0]);
                acc[1] = mfma16(a, lf[1][kt], acc[1]);
            }
#pragma unroll
            for (int c = 0; c < 2; ++c) {
                int col = cn * 16 + c * 64 + lm;
                float bb = lb_s[t * HD + col];
#pragma unroll
                for (int i = 0; i < 4; ++i) {
                    int row = rn * 16 + q * 4 + i;
                    float nh = hreg[c][i] + acc[c][i] + bb;
                    hreg[c][i] = nh;
                    hb_s[row * KP_W + col] = f2bf(nh);
                }
            }
        }
    }

    // ---- output head: sum_a ( ssp(h@ow1+b1) @ ow2 ) + 24*b2
    __syncthreads();   // hb ready, wbuf=ow1 ready
    {
        int rt = w & 1, co = w >> 1;       // C: 32x64 = 2x4 tiles, 8 waves, 1 frag each
        int j = co * 16 + lm;
        f32x4 acc = {};
        const unsigned short* A = &hb_s[(rt * 16 + lm) * KP_W];
        const unsigned short* B = &wbuf_s[j * KP_W];
#pragma unroll
        for (int kt = 0; kt < 4; ++kt)
            acc = mfma16(*(const short8*)(A + kt * 32 + q * 8),
                         *(const short8*)(B + kt * 32 + q * 8), acc);
        float sum = 0.f;
        float bb = ob1_s[j], wo = ow2_s[j];
#pragma unroll
        for (int i = 0; i < 4; ++i) {
            int row = rt * 16 + q * 4 + i;
            if (row < AT) sum += sspf(acc[i] + bb) * wo;
        }
        for (int off = 32; off > 0; off >>= 1) sum += __shfl_down(sum, off);
        if (lane == 0) atomicAdd(&red_s, sum);
    }
    __syncthreads();
    if (tid == 0) out[m] = red_s + (float)AT * out_b2[0];
}

extern "C" void kernel_launch(void* const* d_in, const int* in_sizes, int n_in,
                              void* d_out, int out_size, void* d_ws, size_t ws_size,
                              hipStream_t stream) {
    const int*   z    = (const int*)  d_in[0];
    const float* pos  = (const float*)d_in[1];
    const float* emb  = (const float*)d_in[4];
    const float* mw1  = (const float*)d_in[5];
    const float* mb1  = (const float*)d_in[6];
    const float* mw2  = (const float*)d_in[7];
    const float* mb2  = (const float*)d_in[8];
    const float* l1w  = (const float*)d_in[9];
    const float* l2w  = (const float*)d_in[10];
    const float* l2b  = (const float*)d_in[11];
    const float* lw   = (const float*)d_in[12];
    const float* lb   = (const float*)d_in[13];
    const float* ow1  = (const float*)d_in[14];
    const float* ob1  = (const float*)d_in[15];
    const float* ow2  = (const float*)d_in[16];
    const float* ob2  = (const float*)d_in[17];

    unsigned short* ws = (unsigned short*)d_ws;

    prep<<<dim3(424), dim3(256), 0, stream>>>(l1w, l2w, lw, ow1, mw1, mb1, mw2, mb2, ws);
    schnet_tab<<<dim3(1024), dim3(512), 0, stream>>>(
        z, pos, emb, l2b, lb, ob1, ow2, ob2, ws, (float*)d_out);
}